// Round 1
// baseline (1263.502 us; speedup 1.0000x reference)
//
#include <hip/hip_runtime.h>

#define TT 512
#define BB 32
#define DD 64
#define HH 128
#define EE 256
#define NR 16384   // T*B rows

// ---------- helpers ----------
static __device__ __forceinline__ float bflo(unsigned u){ return __uint_as_float(u << 16); }
static __device__ __forceinline__ float bfhi(unsigned u){ return __uint_as_float(u & 0xFFFF0000u); }
static __device__ __forceinline__ unsigned short f2bf(float x){
  unsigned u = __float_as_uint(x);
  return (unsigned short)((u + 0x7FFFu + ((u >> 16) & 1u)) >> 16);  // RNE
}
static __device__ __forceinline__ unsigned packbf(float a, float b){
  return (unsigned)f2bf(a) | ((unsigned)f2bf(b) << 16);
}
static __device__ __forceinline__ float sigmoidf_(float x){
  return 1.0f / (1.0f + __expf(-x));
}
static __device__ __forceinline__ float tanhf_(float x){
  float e = __expf(2.0f * x);
  return 1.0f - 2.0f / (e + 1.0f);
}

// ---------- K1: gi[dir][j][r] = bi[j] + sum_d (x*mask)[r][d] * Wi[j][d] ----------
// rows r = t*32 + b ; gi stored transposed [384][16384] per dir for coalesced
// stores here and cheap per-step gathers in the scan.
__global__ __launch_bounds__(256) void gi_kernel(
    const float* __restrict__ x, const float* __restrict__ mask,
    const float* __restrict__ WiF, const float* __restrict__ biF,
    const float* __restrict__ WiB, const float* __restrict__ biB,
    float* __restrict__ giT)
{
  int r = blockIdx.x * 256 + threadIdx.x;
  int dir = blockIdx.y;
  const float* Wi = dir ? WiB : WiF;
  const float* bi = dir ? biB : biF;
  float* g = giT + (size_t)dir * 384 * NR;
  int t = r >> 5, b = r & 31;
  const float* xr = x + ((size_t)b * TT + t) * DD;
  const float* mr = mask + ((size_t)b * TT + t) * DD;
  float a[64];
#pragma unroll
  for (int i = 0; i < 16; i++) {
    float4 xv = *(const float4*)(xr + i*4);
    float4 mv = *(const float4*)(mr + i*4);
    a[i*4+0] = xv.x*mv.x; a[i*4+1] = xv.y*mv.y; a[i*4+2] = xv.z*mv.z; a[i*4+3] = xv.w*mv.w;
  }
  for (int j = 0; j < 384; j += 4) {
    float acc0 = bi[j+0], acc1 = bi[j+1], acc2 = bi[j+2], acc3 = bi[j+3];
    const float* w = Wi + (size_t)j * 64;
#pragma unroll
    for (int k = 0; k < 64; k++) {
      float av = a[k];
      acc0 += av * w[k];
      acc1 += av * w[64 + k];
      acc2 += av * w[128 + k];
      acc3 += av * w[192 + k];
    }
    g[(size_t)(j+0)*NR + r] = acc0;
    g[(size_t)(j+1)*NR + r] = acc1;
    g[(size_t)(j+2)*NR + r] = acc2;
    g[(size_t)(j+3)*NR + r] = acc3;
  }
}

// ---------- K2: GRU scan. One WG per (dir, b). 512 threads. ----------
// stage1: j1 = tid>>1 (rz output 0..255), h1 = tid&1 owns 64 of 128 k's.
// stage2: j2 = tid>>2 (n output 0..127),  q2 = tid&3 owns 32 of 128 k's.
// Recurrent weights live in registers (w1[64] + w2[32]).
__global__ __launch_bounds__(512) void scan_kernel(
    const float* __restrict__ giT,
    const float* __restrict__ WhF, const float* __restrict__ bhF,
    const float* __restrict__ WhB, const float* __restrict__ bhB,
    float* __restrict__ hc)
{
  int dir = blockIdx.x >> 5;
  int b = blockIdx.x & 31;
  const float* Wh = dir ? WhB : WhF;
  const float* bh = dir ? bhB : bhF;
  const float* gi = giT + (size_t)dir * 384 * NR;
  int tid = threadIdx.x;
  int j1 = tid >> 1, h1 = tid & 1;
  int j2 = tid >> 2, q2 = tid & 3;

  __shared__ __align__(16) float h_s[128];
  __shared__ __align__(16) float rh_s[128];
  __shared__ float z_s[128];

  float w1[64];
#pragma unroll
  for (int i = 0; i < 16; i++) {
    float4 v = *(const float4*)(Wh + (size_t)j1*128 + h1*64 + i*4);
    w1[i*4+0]=v.x; w1[i*4+1]=v.y; w1[i*4+2]=v.z; w1[i*4+3]=v.w;
  }
  float w2[32];
#pragma unroll
  for (int i = 0; i < 8; i++) {
    float4 v = *(const float4*)(Wh + (size_t)(256+j2)*128 + q2*32 + i*4);
    w2[i*4+0]=v.x; w2[i*4+1]=v.y; w2[i*4+2]=v.z; w2[i*4+3]=v.w;
  }
  float bh1 = bh[j1];
  float bh2 = bh[256 + j2];

  if (tid < 128) h_s[tid] = 0.0f;
  __syncthreads();

  const float* gi1 = gi + (size_t)j1 * NR;
  const float* gi2 = gi + (size_t)(256 + j2) * NR;
  int dt = dir ? -BB : BB;
  int R = dir ? ((TT-1)*BB + b) : b;
  float gi1v = gi1[R], gi2v = gi2[R];

  for (int s = 0; s < TT; s++) {
    // prefetch next step's gi (hidden under compute)
    float gi1n = 0.f, gi2n = 0.f;
    if (s + 1 < TT) { gi1n = gi1[R + dt]; gi2n = gi2[R + dt]; }

    // stage 1: y(j1) = sum_i Wh[j1][i] * h[i]   (this lane: 64 of 128)
    float y = 0.f;
#pragma unroll
    for (int i = 0; i < 16; i++) {
      float4 hv = *(const float4*)(h_s + h1*64 + i*4);
      y += w1[i*4+0]*hv.x + w1[i*4+1]*hv.y + w1[i*4+2]*hv.z + w1[i*4+3]*hv.w;
    }
    y += __shfl_xor(y, 1);
    float pre = gi1v + y + bh1;
    float sg = sigmoidf_(pre);
    if (j1 < 128) {
      if (h1 == 0) rh_s[j1] = sg * h_s[j1];     // r * h (old h)
    } else {
      if (h1 == 0) z_s[j1 - 128] = sg;          // z
    }
    __syncthreads();   // barrier A: rh/z ready

    // stage 2: y2(j2) = sum_i Wh_n[j2][i] * rh[i]  (this lane: 32 of 128)
    float y2 = 0.f;
#pragma unroll
    for (int i = 0; i < 8; i++) {
      float4 rv = *(const float4*)(rh_s + q2*32 + i*4);
      y2 += w2[i*4+0]*rv.x + w2[i*4+1]*rv.y + w2[i*4+2]*rv.z + w2[i*4+3]*rv.w;
    }
    y2 += __shfl_xor(y2, 1);
    y2 += __shfl_xor(y2, 2);
    float nn = tanhf_(gi2v + y2 + bh2);
    float zv = z_s[j2];
    float hv = h_s[j2];                 // old h (read before in-wave write below)
    float hn = nn + zv * (hv - nn);     // (1-z)*n + z*h
    if (q2 == 0) {
      h_s[j2] = hn;
      int t = dir ? (TT - 1 - s) : s;
      hc[((size_t)t * BB + b) * EE + dir * HH + j2] = hn;
    }
    __syncthreads();   // barrier B: h updated for next step
    gi1v = gi1n; gi2v = gi2n;
    R += dt;
  }
}

// ---------- K3/K5: C[r][c] = bias[c] + sum_k A[r][k]*W[c][k]  (K=256) ----------
// A: [16384][256] f32 ; W: [N][256] f32 (bf16-staged in LDS) ; 64 rows/WG.
__global__ __launch_bounds__(256) void gemm_kernel(
    const float* __restrict__ A, const float* __restrict__ W,
    const float* __restrict__ bias, float* __restrict__ C,
    int N, int nChunks)
{
  __shared__ float As[64*258];       // padded stride 258
  __shared__ unsigned Ws[128*129];   // bf16 pairs, padded stride 129 u32
  int tid = threadIdx.x;
  int ty = tid >> 4, tx = tid & 15;
  int r0 = blockIdx.x * 64;

  for (int l = tid; l < 4096; l += 256) {        // 64 rows x 64 float4
    int row = l >> 6, kq = l & 63;
    float4 v = *(const float4*)(A + (size_t)(r0 + row)*256 + kq*4);
    float2* dst = (float2*)&As[row*258 + kq*4];
    dst[0] = make_float2(v.x, v.y);
    dst[1] = make_float2(v.z, v.w);
  }

  for (int ch = 0; ch < nChunks; ch++) {
    int c0 = ch * 128;
    __syncthreads();                               // prior reads of Ws done / As staged
    for (int l = tid; l < 8192; l += 256) {        // 128 cols x 64 float4
      int c = l >> 6, kq = l & 63;
      float4 v = *(const float4*)(W + (size_t)(c0 + c)*256 + kq*4);
      Ws[c*129 + kq*2]     = packbf(v.x, v.y);
      Ws[c*129 + kq*2 + 1] = packbf(v.z, v.w);
    }
    __syncthreads();

    float acc[4][8];
#pragma unroll
    for (int rj = 0; rj < 4; rj++)
#pragma unroll
      for (int cj = 0; cj < 8; cj++)
        acc[rj][cj] = bias[c0 + tx + 16*cj];

#pragma unroll 2
    for (int kp = 0; kp < 128; kp++) {
      float2 av[4];
#pragma unroll
      for (int rj = 0; rj < 4; rj++)
        av[rj] = *(const float2*)&As[(ty*4+rj)*258 + 2*kp];
#pragma unroll
      for (int cj = 0; cj < 8; cj++) {
        unsigned w = Ws[(tx + 16*cj)*129 + kp];
        float w0 = bflo(w), w1 = bfhi(w);
#pragma unroll
        for (int rj = 0; rj < 4; rj++)
          acc[rj][cj] += av[rj].x*w0 + av[rj].y*w1;
      }
    }
#pragma unroll
    for (int rj = 0; rj < 4; rj++)
#pragma unroll
      for (int cj = 0; cj < 8; cj++)
        C[(size_t)(r0 + ty*4 + rj)*N + c0 + tx + 16*cj] = acc[rj][cj];
  }
}

// ---------- K4: attention, one WG per (b, head) ----------
__global__ __launch_bounds__(256) void attn_kernel(
    const float* __restrict__ qkv, float* __restrict__ obuf)
{
  int b = blockIdx.x >> 3, h = blockIdx.x & 7;
  int tid = threadIdx.x;
  __shared__ unsigned short Kt[32][512];        // bf16 K^T [d][s]
  __shared__ __align__(16) float Vs[512][32];   // f32 V
  __shared__ unsigned short Sb[32][520];        // bf16 scores/probs, padded
  __shared__ float Qb[32][33];                  // f32 Q tile, padded

  for (int s = tid; s < 512; s += 256) {
    const float* kr = qkv + ((size_t)s * BB + b) * 768 + 256 + h * 32;
    const float* vr = kr + 256;
#pragma unroll
    for (int dq = 0; dq < 8; dq++) {
      float4 kv = *(const float4*)(kr + dq*4);
      float4 vv = *(const float4*)(vr + dq*4);
      Kt[dq*4+0][s] = f2bf(kv.x);
      Kt[dq*4+1][s] = f2bf(kv.y);
      Kt[dq*4+2][s] = f2bf(kv.z);
      Kt[dq*4+3][s] = f2bf(kv.w);
      *(float4*)&Vs[s][dq*4] = vv;
    }
  }

  int ty = tid >> 4, tx = tid & 15;   // scores roles: 2 rows x 8 cols
  int rr = tid >> 3, lg = tid & 7;    // softmax/PV roles
  int d0 = (tid & 7) * 4;

  for (int rb = 0; rb < 16; rb++) {
    int t0 = rb * 32;
    __syncthreads();   // K/V staged (rb=0) ; Qb/Sb free for rewrite
    for (int l = tid; l < 1024; l += 256) {
      int tr = l >> 5, d = l & 31;
      Qb[tr][d] = qkv[((size_t)(t0 + tr) * BB + b) * 768 + h * 32 + d] * 0.17677669529663687f;
    }
    __syncthreads();

    // scores
    for (int c4 = 0; c4 < 4; c4++) {
      int s0 = c4 * 128 + tx * 8;
      float acc0[8] = {0,0,0,0,0,0,0,0};
      float acc1[8] = {0,0,0,0,0,0,0,0};
#pragma unroll 8
      for (int d = 0; d < 32; d++) {
        float q0 = Qb[ty*2+0][d];
        float q1 = Qb[ty*2+1][d];
        uint4 kw = *(const uint4*)&Kt[d][s0];
        float k0 = bflo(kw.x), k1 = bfhi(kw.x);
        float k2 = bflo(kw.y), k3 = bfhi(kw.y);
        float k4 = bflo(kw.z), k5 = bfhi(kw.z);
        float k6 = bflo(kw.w), k7 = bfhi(kw.w);
        acc0[0]+=q0*k0; acc0[1]+=q0*k1; acc0[2]+=q0*k2; acc0[3]+=q0*k3;
        acc0[4]+=q0*k4; acc0[5]+=q0*k5; acc0[6]+=q0*k6; acc0[7]+=q0*k7;
        acc1[0]+=q1*k0; acc1[1]+=q1*k1; acc1[2]+=q1*k2; acc1[3]+=q1*k3;
        acc1[4]+=q1*k4; acc1[5]+=q1*k5; acc1[6]+=q1*k6; acc1[7]+=q1*k7;
      }
      unsigned* s0p = (unsigned*)&Sb[ty*2+0][s0];
      unsigned* s1p = (unsigned*)&Sb[ty*2+1][s0];
      s0p[0]=packbf(acc0[0],acc0[1]); s0p[1]=packbf(acc0[2],acc0[3]);
      s0p[2]=packbf(acc0[4],acc0[5]); s0p[3]=packbf(acc0[6],acc0[7]);
      s1p[0]=packbf(acc1[0],acc1[1]); s1p[1]=packbf(acc1[2],acc1[3]);
      s1p[2]=packbf(acc1[4],acc1[5]); s1p[3]=packbf(acc1[6],acc1[7]);
    }
    __syncthreads();

    // softmax over s (row rr, 8 lanes per row, strided columns)
    {
      unsigned* srow = (unsigned*)&Sb[rr][0];
      float vals[64];
      float m = -1e30f;
#pragma unroll
      for (int i = 0; i < 32; i++) {
        unsigned u = srow[lg + i*8];
        float va = bflo(u), vb = bfhi(u);
        vals[i*2] = va; vals[i*2+1] = vb;
        m = fmaxf(m, fmaxf(va, vb));
      }
      m = fmaxf(m, __shfl_xor(m, 1));
      m = fmaxf(m, __shfl_xor(m, 2));
      m = fmaxf(m, __shfl_xor(m, 4));
      float sum = 0.f;
#pragma unroll
      for (int i = 0; i < 64; i++) { float e = __expf(vals[i] - m); vals[i] = e; sum += e; }
      sum += __shfl_xor(sum, 1);
      sum += __shfl_xor(sum, 2);
      sum += __shfl_xor(sum, 4);
      float inv = 1.0f / sum;
#pragma unroll
      for (int i = 0; i < 32; i++)
        srow[lg + i*8] = packbf(vals[i*2]*inv, vals[i*2+1]*inv);
    }
    __syncthreads();

    // PV: o[rr][d0..d0+3]
    {
      float4 acc = make_float4(0,0,0,0);
#pragma unroll 4
      for (int s = 0; s < 512; s += 4) {
        uint2 pw = *(const uint2*)&Sb[rr][s];
        float p0 = bflo(pw.x), p1 = bfhi(pw.x), p2 = bflo(pw.y), p3 = bfhi(pw.y);
        float4 v0 = *(const float4*)&Vs[s+0][d0];
        float4 v1 = *(const float4*)&Vs[s+1][d0];
        float4 v2 = *(const float4*)&Vs[s+2][d0];
        float4 v3 = *(const float4*)&Vs[s+3][d0];
        acc.x += p0*v0.x + p1*v1.x + p2*v2.x + p3*v3.x;
        acc.y += p0*v0.y + p1*v1.y + p2*v2.y + p3*v3.y;
        acc.z += p0*v0.z + p1*v1.z + p2*v2.z + p3*v3.z;
        acc.w += p0*v0.w + p1*v1.w + p2*v2.w + p3*v3.w;
      }
      *(float4*)(obuf + ((size_t)(t0 + rr) * BB + b) * EE + h*32 + d0) = acc;
    }
  }
}

// ---------- K6: imputed = hc2 @ out_w.T + out_b ; blend ; write both outputs ----------
__global__ __launch_bounds__(256) void final_kernel(
    const float* __restrict__ A,      // hc2 [16384][256]
    const float* __restrict__ W,      // out_w [64][256]
    const float* __restrict__ bias,   // out_b [64]
    const float* __restrict__ x, const float* __restrict__ mask,
    float* __restrict__ out)          // [output | imputed], each [B][T][D]
{
  __shared__ float As[64*258];
  __shared__ unsigned Ws[64*129];
  int tid = threadIdx.x;
  int ty = tid >> 4, tx = tid & 15;
  int r0 = blockIdx.x * 64;

  for (int l = tid; l < 4096; l += 256) {
    int row = l >> 6, kq = l & 63;
    float4 v = *(const float4*)(A + (size_t)(r0 + row)*256 + kq*4);
    float2* dst = (float2*)&As[row*258 + kq*4];
    dst[0] = make_float2(v.x, v.y);
    dst[1] = make_float2(v.z, v.w);
  }
  for (int l = tid; l < 4096; l += 256) {
    int c = l >> 6, kq = l & 63;
    float4 v = *(const float4*)(W + (size_t)c*256 + kq*4);
    Ws[c*129 + kq*2]     = packbf(v.x, v.y);
    Ws[c*129 + kq*2 + 1] = packbf(v.z, v.w);
  }
  __syncthreads();

  float acc[4][4];
#pragma unroll
  for (int rj = 0; rj < 4; rj++)
#pragma unroll
    for (int cj = 0; cj < 4; cj++)
      acc[rj][cj] = bias[tx + 16*cj];

#pragma unroll 2
  for (int kp = 0; kp < 128; kp++) {
    float2 av[4];
#pragma unroll
    for (int rj = 0; rj < 4; rj++)
      av[rj] = *(const float2*)&As[(ty*4+rj)*258 + 2*kp];
#pragma unroll
    for (int cj = 0; cj < 4; cj++) {
      unsigned w = Ws[(tx + 16*cj)*129 + kp];
      float w0 = bflo(w), w1 = bfhi(w);
#pragma unroll
      for (int rj = 0; rj < 4; rj++)
        acc[rj][cj] += av[rj].x*w0 + av[rj].y*w1;
    }
  }

#pragma unroll
  for (int rj = 0; rj < 4; rj++) {
    int r = r0 + ty*4 + rj;
    int t = r >> 5, b = r & 31;
    size_t base = ((size_t)b * TT + t) * DD;
#pragma unroll
    for (int cj = 0; cj < 4; cj++) {
      int c = tx + 16*cj;
      float imp = acc[rj][cj];
      float xv = x[base + c], mv = mask[base + c];
      out[base + c] = xv*mv + imp*(1.0f - mv);
      out[(size_t)1048576 + base + c] = imp;
    }
  }
}

// ---------- launcher ----------
extern "C" void kernel_launch(void* const* d_in, const int* in_sizes, int n_in,
                              void* d_out, int out_size, void* d_ws, size_t ws_size,
                              hipStream_t stream) {
  const float* x     = (const float*)d_in[0];
  const float* mask  = (const float*)d_in[1];
  const float* fWi   = (const float*)d_in[2];
  const float* fbi   = (const float*)d_in[3];
  const float* fWh   = (const float*)d_in[4];
  const float* fbh   = (const float*)d_in[5];
  const float* bWi   = (const float*)d_in[6];
  const float* bbi   = (const float*)d_in[7];
  const float* bWh   = (const float*)d_in[8];
  const float* bbh   = (const float*)d_in[9];
  const float* aWin  = (const float*)d_in[10];
  const float* abin  = (const float*)d_in[11];
  const float* aWout = (const float*)d_in[12];
  const float* about = (const float*)d_in[13];
  const float* oW    = (const float*)d_in[14];
  const float* ob    = (const float*)d_in[15];
  float* out = (float*)d_out;
  float* ws  = (float*)d_ws;

  // workspace layout (f32 elems), with aliasing across pipeline phases:
  // [0, 12582912)        giT [2][384][16384]  -> later qkv [16384][768] -> later hc2 [16384][256]
  // [12582912, 16777216) hc  [16384][256]     -> later obuf [16384][256]
  float* giT  = ws;
  float* hc   = ws + 12582912;
  float* qkv  = ws;
  float* obuf = ws + 12582912;
  float* hc2  = ws;

  gi_kernel<<<dim3(64, 2), 256, 0, stream>>>(x, mask, fWi, fbi, bWi, bbi, giT);
  scan_kernel<<<64, 512, 0, stream>>>(giT, fWh, fbh, bWh, bbh, hc);
  gemm_kernel<<<256, 256, 0, stream>>>(hc, aWin, abin, qkv, 768, 6);
  attn_kernel<<<256, 256, 0, stream>>>(qkv, obuf);
  gemm_kernel<<<256, 256, 0, stream>>>(obuf, aWout, about, hc2, 256, 2);
  final_kernel<<<256, 256, 0, stream>>>(hc2, oW, ob, x, mask, out);
}

// Round 2
// 1231.236 us; speedup vs baseline: 1.0262x; 1.0262x over previous
//
#include <hip/hip_runtime.h>

#define TT 512
#define BB 32
#define DD 64
#define HH 128
#define EE 256
#define NR 16384   // T*B rows

// ---------- helpers ----------
static __device__ __forceinline__ float bflo(unsigned u){ return __uint_as_float(u << 16); }
static __device__ __forceinline__ float bfhi(unsigned u){ return __uint_as_float(u & 0xFFFF0000u); }
static __device__ __forceinline__ unsigned short f2bf(float x){
  unsigned u = __float_as_uint(x);
  return (unsigned short)((u + 0x7FFFu + ((u >> 16) & 1u)) >> 16);  // RNE
}
static __device__ __forceinline__ unsigned packbf(float a, float b){
  return (unsigned)f2bf(a) | ((unsigned)f2bf(b) << 16);
}
static __device__ __forceinline__ float sigmoidf_(float x){
  return 1.0f / (1.0f + __expf(-x));
}
static __device__ __forceinline__ float tanhf_(float x){
  float e = __expf(2.0f * x);
  return 1.0f - 2.0f / (e + 1.0f);
}

// ---------- K1: gi[r][dir*384+j] = bi[j] + sum_d (x*mask)[r][d] * Wi[j][d] ----------
// rows r = t*32 + b ; gi row-major [16384][768] so the scan's per-step WG read
// is a contiguous 1.5KB slab (coalesced, prefetch-friendly).
__global__ __launch_bounds__(256, 2) void gi_kernel(
    const float* __restrict__ x, const float* __restrict__ mask,
    const float* __restrict__ WiF, const float* __restrict__ biF,
    const float* __restrict__ WiB, const float* __restrict__ biB,
    float* __restrict__ gi)
{
  int r = blockIdx.x * 256 + threadIdx.x;
  int dir = blockIdx.y;
  const float* Wi = dir ? WiB : WiF;
  const float* bi = dir ? biB : biF;
  int t = r >> 5, b = r & 31;
  const float* xr = x + ((size_t)b * TT + t) * DD;
  const float* mr = mask + ((size_t)b * TT + t) * DD;
  float a[64];
#pragma unroll
  for (int i = 0; i < 16; i++) {
    float4 xv = *(const float4*)(xr + i*4);
    float4 mv = *(const float4*)(mr + i*4);
    a[i*4+0] = xv.x*mv.x; a[i*4+1] = xv.y*mv.y; a[i*4+2] = xv.z*mv.z; a[i*4+3] = xv.w*mv.w;
  }
  float* g = gi + (size_t)r * 768 + dir * 384;
  for (int j = 0; j < 384; j += 4) {
    float acc0 = bi[j+0], acc1 = bi[j+1], acc2 = bi[j+2], acc3 = bi[j+3];
    const float* w = Wi + (size_t)j * 64;
#pragma unroll
    for (int k = 0; k < 64; k++) {
      float av = a[k];
      acc0 += av * w[k];
      acc1 += av * w[64 + k];
      acc2 += av * w[128 + k];
      acc3 += av * w[192 + k];
    }
    *(float4*)(g + j) = make_float4(acc0, acc1, acc2, acc3);
  }
}

// ---------- K2: GRU scan. One WG per (dir, b). 512 threads, 2 waves/SIMD. ----------
// stage1: j1 = tid>>1 (rz output 0..255), h1 = tid&1 owns 64 of 128 k's.
// stage2: j2 = tid>>2 (n output 0..127),  q2 = tid&3 owns 32 of 128 k's.
// Recurrent weights in NAMED float4 registers (no array -> no scratch/remat).
__global__ __launch_bounds__(512, 2) void scan_kernel(
    const float* __restrict__ gi,      // [16384][768]
    const float* __restrict__ WhF, const float* __restrict__ bhF,
    const float* __restrict__ WhB, const float* __restrict__ bhB,
    float* __restrict__ hc)
{
  int dir = blockIdx.x >> 5;
  int b = blockIdx.x & 31;
  const float* Wh = dir ? WhB : WhF;
  const float* bh = dir ? bhB : bhF;
  int tid = threadIdx.x;
  int j1 = tid >> 1, h1 = tid & 1;
  int j2 = tid >> 2, q2 = tid & 3;

  __shared__ __align__(16) float h_s[128];
  __shared__ __align__(16) float rh_s[160];   // 4 chunks of 32, padded +8 -> bases 0,40,80,120
  __shared__ float z_s[128];

  const float* wp1 = Wh + (size_t)j1 * 128 + h1 * 64;
  float4 w1_0  = *(const float4*)(wp1 +  0);
  float4 w1_1  = *(const float4*)(wp1 +  4);
  float4 w1_2  = *(const float4*)(wp1 +  8);
  float4 w1_3  = *(const float4*)(wp1 + 12);
  float4 w1_4  = *(const float4*)(wp1 + 16);
  float4 w1_5  = *(const float4*)(wp1 + 20);
  float4 w1_6  = *(const float4*)(wp1 + 24);
  float4 w1_7  = *(const float4*)(wp1 + 28);
  float4 w1_8  = *(const float4*)(wp1 + 32);
  float4 w1_9  = *(const float4*)(wp1 + 36);
  float4 w1_10 = *(const float4*)(wp1 + 40);
  float4 w1_11 = *(const float4*)(wp1 + 44);
  float4 w1_12 = *(const float4*)(wp1 + 48);
  float4 w1_13 = *(const float4*)(wp1 + 52);
  float4 w1_14 = *(const float4*)(wp1 + 56);
  float4 w1_15 = *(const float4*)(wp1 + 60);
  const float* wp2 = Wh + (size_t)(256 + j2) * 128 + q2 * 32;
  float4 w2_0 = *(const float4*)(wp2 +  0);
  float4 w2_1 = *(const float4*)(wp2 +  4);
  float4 w2_2 = *(const float4*)(wp2 +  8);
  float4 w2_3 = *(const float4*)(wp2 + 12);
  float4 w2_4 = *(const float4*)(wp2 + 16);
  float4 w2_5 = *(const float4*)(wp2 + 20);
  float4 w2_6 = *(const float4*)(wp2 + 24);
  float4 w2_7 = *(const float4*)(wp2 + 28);

  float bh1 = bh[j1];
  float bh2 = bh[256 + j2];

  if (tid < 128) h_s[tid] = 0.0f;
  __syncthreads();

  size_t row0 = dir ? ((size_t)(TT-1)*BB + b) : (size_t)b;
  const float* grow = gi + row0 * 768 + dir * 384;
  long dstep = (dir ? -(long)BB : (long)BB) * 768;
  float gi1v = grow[j1];
  float gi2v = grow[256 + j2];

  for (int s = 0; s < TT; s++) {
    // prefetch next step's gi (coalesced; hidden under this step's compute)
    const float* gnext = grow + dstep;
    float gi1n = 0.f, gi2n = 0.f;
    if (s + 1 < TT) { gi1n = gnext[j1]; gi2n = gnext[256 + j2]; }

    // stage 1: y(j1) = sum_i Wh[j1][i] * h[i]   (this lane: 64 of 128)
    float a0 = 0.f, a1 = 0.f, a2 = 0.f, a3 = 0.f;
#define FMA1(n) { float4 hv = *(const float4*)(h_s + h1*64 + 4*(n)); \
    a0 += w1_##n.x*hv.x; a1 += w1_##n.y*hv.y; a2 += w1_##n.z*hv.z; a3 += w1_##n.w*hv.w; }
    FMA1(0) FMA1(1) FMA1(2) FMA1(3) FMA1(4) FMA1(5) FMA1(6) FMA1(7)
    FMA1(8) FMA1(9) FMA1(10) FMA1(11) FMA1(12) FMA1(13) FMA1(14) FMA1(15)
#undef FMA1
    float y = (a0 + a1) + (a2 + a3);
    y += __shfl_xor(y, 1);
    float sg = sigmoidf_(gi1v + y + bh1);
    if (h1 == 0) {
      if (j1 < 128) rh_s[j1 + 8*(j1 >> 5)] = sg * h_s[j1];   // r * h (old h), padded
      else          z_s[j1 - 128] = sg;                      // z
    }
    __syncthreads();   // barrier A: rh/z ready

    // stage 2: y2(j2) = sum_i Wh_n[j2][i] * rh[i]  (this lane: 32 of 128)
    const float* rp = rh_s + q2 * 40;
    float b0 = 0.f, b1 = 0.f, b2 = 0.f, b3 = 0.f;
#define FMA2(n) { float4 rv = *(const float4*)(rp + 4*(n)); \
    b0 += w2_##n.x*rv.x; b1 += w2_##n.y*rv.y; b2 += w2_##n.z*rv.z; b3 += w2_##n.w*rv.w; }
    FMA2(0) FMA2(1) FMA2(2) FMA2(3) FMA2(4) FMA2(5) FMA2(6) FMA2(7)
#undef FMA2
    float y2 = (b0 + b1) + (b2 + b3);
    y2 += __shfl_xor(y2, 1);
    y2 += __shfl_xor(y2, 2);
    float nn = tanhf_(gi2v + y2 + bh2);
    float zv = z_s[j2];
    float hv = h_s[j2];                 // old h (read before in-wave write below)
    float hn = nn + zv * (hv - nn);     // (1-z)*n + z*h
    if (q2 == 0) {
      h_s[j2] = hn;
      int t = dir ? (TT - 1 - s) : s;
      hc[((size_t)t * BB + b) * EE + dir * HH + j2] = hn;
    }
    __syncthreads();   // barrier B: h updated for next step
    gi1v = gi1n; gi2v = gi2n;
    grow = gnext;
  }
}

// ---------- K3/K5: C[r][c] = bias[c] + sum_k A[r][k]*W[c][k]  (K=256) ----------
// A: [16384][256] f32 ; W: [N][256] f32 (bf16-staged in LDS) ; 64 rows/WG.
__global__ __launch_bounds__(256) void gemm_kernel(
    const float* __restrict__ A, const float* __restrict__ W,
    const float* __restrict__ bias, float* __restrict__ C,
    int N, int nChunks)
{
  __shared__ float As[64*258];       // padded stride 258
  __shared__ unsigned Ws[128*129];   // bf16 pairs, padded stride 129 u32
  int tid = threadIdx.x;
  int ty = tid >> 4, tx = tid & 15;
  int r0 = blockIdx.x * 64;

  for (int l = tid; l < 4096; l += 256) {        // 64 rows x 64 float4
    int row = l >> 6, kq = l & 63;
    float4 v = *(const float4*)(A + (size_t)(r0 + row)*256 + kq*4);
    float2* dst = (float2*)&As[row*258 + kq*4];
    dst[0] = make_float2(v.x, v.y);
    dst[1] = make_float2(v.z, v.w);
  }

  for (int ch = 0; ch < nChunks; ch++) {
    int c0 = ch * 128;
    __syncthreads();                               // prior reads of Ws done / As staged
    for (int l = tid; l < 8192; l += 256) {        // 128 cols x 64 float4
      int c = l >> 6, kq = l & 63;
      float4 v = *(const float4*)(W + (size_t)(c0 + c)*256 + kq*4);
      Ws[c*129 + kq*2]     = packbf(v.x, v.y);
      Ws[c*129 + kq*2 + 1] = packbf(v.z, v.w);
    }
    __syncthreads();

    float acc[4][8];
#pragma unroll
    for (int rj = 0; rj < 4; rj++)
#pragma unroll
      for (int cj = 0; cj < 8; cj++)
        acc[rj][cj] = bias[c0 + tx + 16*cj];

#pragma unroll 2
    for (int kp = 0; kp < 128; kp++) {
      float2 av[4];
#pragma unroll
      for (int rj = 0; rj < 4; rj++)
        av[rj] = *(const float2*)&As[(ty*4+rj)*258 + 2*kp];
#pragma unroll
      for (int cj = 0; cj < 8; cj++) {
        unsigned w = Ws[(tx + 16*cj)*129 + kp];
        float w0 = bflo(w), w1 = bfhi(w);
#pragma unroll
        for (int rj = 0; rj < 4; rj++)
          acc[rj][cj] += av[rj].x*w0 + av[rj].y*w1;
      }
    }
#pragma unroll
    for (int rj = 0; rj < 4; rj++)
#pragma unroll
      for (int cj = 0; cj < 8; cj++)
        C[(size_t)(r0 + ty*4 + rj)*N + c0 + tx + 16*cj] = acc[rj][cj];
  }
}

// ---------- K4: attention, one WG per (b, head) ----------
__global__ __launch_bounds__(256) void attn_kernel(
    const float* __restrict__ qkv, float* __restrict__ obuf)
{
  int b = blockIdx.x >> 3, h = blockIdx.x & 7;
  int tid = threadIdx.x;
  __shared__ unsigned short Kt[32][512];        // bf16 K^T [d][s]
  __shared__ __align__(16) float Vs[512][32];   // f32 V
  __shared__ unsigned short Sb[32][520];        // bf16 scores/probs, padded
  __shared__ float Qb[32][33];                  // f32 Q tile, padded

  for (int s = tid; s < 512; s += 256) {
    const float* kr = qkv + ((size_t)s * BB + b) * 768 + 256 + h * 32;
    const float* vr = kr + 256;
#pragma unroll
    for (int dq = 0; dq < 8; dq++) {
      float4 kv = *(const float4*)(kr + dq*4);
      float4 vv = *(const float4*)(vr + dq*4);
      Kt[dq*4+0][s] = f2bf(kv.x);
      Kt[dq*4+1][s] = f2bf(kv.y);
      Kt[dq*4+2][s] = f2bf(kv.z);
      Kt[dq*4+3][s] = f2bf(kv.w);
      *(float4*)&Vs[s][dq*4] = vv;
    }
  }

  int ty = tid >> 4, tx = tid & 15;   // scores roles: 2 rows x 8 cols
  int rr = tid >> 3, lg = tid & 7;    // softmax/PV roles
  int d0 = (tid & 7) * 4;

  for (int rb = 0; rb < 16; rb++) {
    int t0 = rb * 32;
    __syncthreads();   // K/V staged (rb=0) ; Qb/Sb free for rewrite
    for (int l = tid; l < 1024; l += 256) {
      int tr = l >> 5, d = l & 31;
      Qb[tr][d] = qkv[((size_t)(t0 + tr) * BB + b) * 768 + h * 32 + d] * 0.17677669529663687f;
    }
    __syncthreads();

    // scores
    for (int c4 = 0; c4 < 4; c4++) {
      int s0 = c4 * 128 + tx * 8;
      float acc0[8] = {0,0,0,0,0,0,0,0};
      float acc1[8] = {0,0,0,0,0,0,0,0};
#pragma unroll 8
      for (int d = 0; d < 32; d++) {
        float q0 = Qb[ty*2+0][d];
        float q1 = Qb[ty*2+1][d];
        uint4 kw = *(const uint4*)&Kt[d][s0];
        float k0 = bflo(kw.x), k1 = bfhi(kw.x);
        float k2 = bflo(kw.y), k3 = bfhi(kw.y);
        float k4 = bflo(kw.z), k5 = bfhi(kw.z);
        float k6 = bflo(kw.w), k7 = bfhi(kw.w);
        acc0[0]+=q0*k0; acc0[1]+=q0*k1; acc0[2]+=q0*k2; acc0[3]+=q0*k3;
        acc0[4]+=q0*k4; acc0[5]+=q0*k5; acc0[6]+=q0*k6; acc0[7]+=q0*k7;
        acc1[0]+=q1*k0; acc1[1]+=q1*k1; acc1[2]+=q1*k2; acc1[3]+=q1*k3;
        acc1[4]+=q1*k4; acc1[5]+=q1*k5; acc1[6]+=q1*k6; acc1[7]+=q1*k7;
      }
      unsigned* s0p = (unsigned*)&Sb[ty*2+0][s0];
      unsigned* s1p = (unsigned*)&Sb[ty*2+1][s0];
      s0p[0]=packbf(acc0[0],acc0[1]); s0p[1]=packbf(acc0[2],acc0[3]);
      s0p[2]=packbf(acc0[4],acc0[5]); s0p[3]=packbf(acc0[6],acc0[7]);
      s1p[0]=packbf(acc1[0],acc1[1]); s1p[1]=packbf(acc1[2],acc1[3]);
      s1p[2]=packbf(acc1[4],acc1[5]); s1p[3]=packbf(acc1[6],acc1[7]);
    }
    __syncthreads();

    // softmax over s (row rr, 8 lanes per row, strided columns)
    {
      unsigned* srow = (unsigned*)&Sb[rr][0];
      float vals[64];
      float m = -1e30f;
#pragma unroll
      for (int i = 0; i < 32; i++) {
        unsigned u = srow[lg + i*8];
        float va = bflo(u), vb = bfhi(u);
        vals[i*2] = va; vals[i*2+1] = vb;
        m = fmaxf(m, fmaxf(va, vb));
      }
      m = fmaxf(m, __shfl_xor(m, 1));
      m = fmaxf(m, __shfl_xor(m, 2));
      m = fmaxf(m, __shfl_xor(m, 4));
      float sum = 0.f;
#pragma unroll
      for (int i = 0; i < 64; i++) { float e = __expf(vals[i] - m); vals[i] = e; sum += e; }
      sum += __shfl_xor(sum, 1);
      sum += __shfl_xor(sum, 2);
      sum += __shfl_xor(sum, 4);
      float inv = 1.0f / sum;
#pragma unroll
      for (int i = 0; i < 32; i++)
        srow[lg + i*8] = packbf(vals[i*2]*inv, vals[i*2+1]*inv);
    }
    __syncthreads();

    // PV: o[rr][d0..d0+3]
    {
      float4 acc = make_float4(0,0,0,0);
#pragma unroll 4
      for (int s = 0; s < 512; s += 4) {
        uint2 pw = *(const uint2*)&Sb[rr][s];
        float p0 = bflo(pw.x), p1 = bfhi(pw.x), p2 = bflo(pw.y), p3 = bfhi(pw.y);
        float4 v0 = *(const float4*)&Vs[s+0][d0];
        float4 v1 = *(const float4*)&Vs[s+1][d0];
        float4 v2 = *(const float4*)&Vs[s+2][d0];
        float4 v3 = *(const float4*)&Vs[s+3][d0];
        acc.x += p0*v0.x + p1*v1.x + p2*v2.x + p3*v3.x;
        acc.y += p0*v0.y + p1*v1.y + p2*v2.y + p3*v3.y;
        acc.z += p0*v0.z + p1*v1.z + p2*v2.z + p3*v3.z;
        acc.w += p0*v0.w + p1*v1.w + p2*v2.w + p3*v3.w;
      }
      *(float4*)(obuf + ((size_t)(t0 + rr) * BB + b) * EE + h*32 + d0) = acc;
    }
  }
}

// ---------- K6: imputed = hc2 @ out_w.T + out_b ; blend ; write both outputs ----------
__global__ __launch_bounds__(256) void final_kernel(
    const float* __restrict__ A,      // hc2 [16384][256]
    const float* __restrict__ W,      // out_w [64][256]
    const float* __restrict__ bias,   // out_b [64]
    const float* __restrict__ x, const float* __restrict__ mask,
    float* __restrict__ out)          // [output | imputed], each [B][T][D]
{
  __shared__ float As[64*258];
  __shared__ unsigned Ws[64*129];
  int tid = threadIdx.x;
  int ty = tid >> 4, tx = tid & 15;
  int r0 = blockIdx.x * 64;

  for (int l = tid; l < 4096; l += 256) {
    int row = l >> 6, kq = l & 63;
    float4 v = *(const float4*)(A + (size_t)(r0 + row)*256 + kq*4);
    float2* dst = (float2*)&As[row*258 + kq*4];
    dst[0] = make_float2(v.x, v.y);
    dst[1] = make_float2(v.z, v.w);
  }
  for (int l = tid; l < 4096; l += 256) {
    int c = l >> 6, kq = l & 63;
    float4 v = *(const float4*)(W + (size_t)c*256 + kq*4);
    Ws[c*129 + kq*2]     = packbf(v.x, v.y);
    Ws[c*129 + kq*2 + 1] = packbf(v.z, v.w);
  }
  __syncthreads();

  float acc[4][4];
#pragma unroll
  for (int rj = 0; rj < 4; rj++)
#pragma unroll
    for (int cj = 0; cj < 4; cj++)
      acc[rj][cj] = bias[tx + 16*cj];

#pragma unroll 2
  for (int kp = 0; kp < 128; kp++) {
    float2 av[4];
#pragma unroll
    for (int rj = 0; rj < 4; rj++)
      av[rj] = *(const float2*)&As[(ty*4+rj)*258 + 2*kp];
#pragma unroll
    for (int cj = 0; cj < 4; cj++) {
      unsigned w = Ws[(tx + 16*cj)*129 + kp];
      float w0 = bflo(w), w1 = bfhi(w);
#pragma unroll
      for (int rj = 0; rj < 4; rj++)
        acc[rj][cj] += av[rj].x*w0 + av[rj].y*w1;
    }
  }

#pragma unroll
  for (int rj = 0; rj < 4; rj++) {
    int r = r0 + ty*4 + rj;
    int t = r >> 5, b = r & 31;
    size_t base = ((size_t)b * TT + t) * DD;
#pragma unroll
    for (int cj = 0; cj < 4; cj++) {
      int c = tx + 16*cj;
      float imp = acc[rj][cj];
      float xv = x[base + c], mv = mask[base + c];
      out[base + c] = xv*mv + imp*(1.0f - mv);
      out[(size_t)1048576 + base + c] = imp;
    }
  }
}

// ---------- launcher ----------
extern "C" void kernel_launch(void* const* d_in, const int* in_sizes, int n_in,
                              void* d_out, int out_size, void* d_ws, size_t ws_size,
                              hipStream_t stream) {
  const float* x     = (const float*)d_in[0];
  const float* mask  = (const float*)d_in[1];
  const float* fWi   = (const float*)d_in[2];
  const float* fbi   = (const float*)d_in[3];
  const float* fWh   = (const float*)d_in[4];
  const float* fbh   = (const float*)d_in[5];
  const float* bWi   = (const float*)d_in[6];
  const float* bbi   = (const float*)d_in[7];
  const float* bWh   = (const float*)d_in[8];
  const float* bbh   = (const float*)d_in[9];
  const float* aWin  = (const float*)d_in[10];
  const float* abin  = (const float*)d_in[11];
  const float* aWout = (const float*)d_in[12];
  const float* about = (const float*)d_in[13];
  const float* oW    = (const float*)d_in[14];
  const float* ob    = (const float*)d_in[15];
  float* out = (float*)d_out;
  float* ws  = (float*)d_ws;

  // workspace layout (f32 elems), with aliasing across pipeline phases:
  // [0, 12582912)        gi [16384][768]  -> later qkv [16384][768] -> later hc2 [16384][256]
  // [12582912, 16777216) hc  [16384][256] -> later obuf [16384][256]
  float* gi   = ws;
  float* hc   = ws + 12582912;
  float* qkv  = ws;
  float* obuf = ws + 12582912;
  float* hc2  = ws;

  gi_kernel<<<dim3(64, 2), 256, 0, stream>>>(x, mask, fWi, fbi, bWi, bbi, gi);
  scan_kernel<<<64, 512, 0, stream>>>(gi, fWh, fbh, bWh, bbh, hc);
  gemm_kernel<<<256, 256, 0, stream>>>(hc, aWin, abin, qkv, 768, 6);
  attn_kernel<<<256, 256, 0, stream>>>(qkv, obuf);
  gemm_kernel<<<256, 256, 0, stream>>>(obuf, aWout, about, hc2, 256, 2);
  final_kernel<<<256, 256, 0, stream>>>(hc2, oW, ob, x, mask, out);
}

// Round 4
// 1173.059 us; speedup vs baseline: 1.0771x; 1.0496x over previous
//
#include <hip/hip_runtime.h>

#define TT 512
#define BB 32
#define DD 64
#define HH 128
#define EE 256
#define NR 16384   // T*B rows

typedef _Float16 h2v __attribute__((ext_vector_type(2)));

// ---------- helpers ----------
static __device__ __forceinline__ float bflo(unsigned u){ return __uint_as_float(u << 16); }
static __device__ __forceinline__ float bfhi(unsigned u){ return __uint_as_float(u & 0xFFFF0000u); }
static __device__ __forceinline__ unsigned short f2bf(float x){
  unsigned u = __float_as_uint(x);
  return (unsigned short)((u + 0x7FFFu + ((u >> 16) & 1u)) >> 16);  // RNE
}
static __device__ __forceinline__ unsigned packbf(float a, float b){
  return (unsigned)f2bf(a) | ((unsigned)f2bf(b) << 16);
}
static __device__ __forceinline__ float sigmoidf_(float x){
  return 1.0f / (1.0f + __expf(-x));
}
static __device__ __forceinline__ float tanhf_(float x){
  float e = __expf(2.0f * x);
  return 1.0f - 2.0f / (e + 1.0f);
}
static __device__ __forceinline__ unsigned packh2(float a, float b){
  h2v v; v.x = (_Float16)a; v.y = (_Float16)b;
  return __builtin_bit_cast(unsigned, v);
}
#define BCH(u) __builtin_bit_cast(h2v, (u))
#define DOT2(a, b, c) __builtin_amdgcn_fdot2((a), (b), (c), false)

// ---------- K1: gi[r][dir*384+j] = bi[j] + sum_d (x*mask)[r][d] * Wi[j][d] ----------
__global__ __launch_bounds__(256, 2) void gi_kernel(
    const float* __restrict__ x, const float* __restrict__ mask,
    const float* __restrict__ WiF, const float* __restrict__ biF,
    const float* __restrict__ WiB, const float* __restrict__ biB,
    float* __restrict__ gi)
{
  int r = blockIdx.x * 256 + threadIdx.x;
  int dir = blockIdx.y;
  const float* Wi = dir ? WiB : WiF;
  const float* bi = dir ? biB : biF;
  int t = r >> 5, b = r & 31;
  const float* xr = x + ((size_t)b * TT + t) * DD;
  const float* mr = mask + ((size_t)b * TT + t) * DD;
  float a[64];
#pragma unroll
  for (int i = 0; i < 16; i++) {
    float4 xv = *(const float4*)(xr + i*4);
    float4 mv = *(const float4*)(mr + i*4);
    a[i*4+0] = xv.x*mv.x; a[i*4+1] = xv.y*mv.y; a[i*4+2] = xv.z*mv.z; a[i*4+3] = xv.w*mv.w;
  }
  float* g = gi + (size_t)r * 768 + dir * 384;
  for (int j = 0; j < 384; j += 4) {
    float acc0 = bi[j+0], acc1 = bi[j+1], acc2 = bi[j+2], acc3 = bi[j+3];
    const float* w = Wi + (size_t)j * 64;
#pragma unroll
    for (int k = 0; k < 64; k++) {
      float av = a[k];
      acc0 += av * w[k];
      acc1 += av * w[64 + k];
      acc2 += av * w[128 + k];
      acc3 += av * w[192 + k];
    }
    *(float4*)(g + j) = make_float4(acc0, acc1, acc2, acc3);
  }
}

// ---------- K2: GRU scan. One WG per (dir, b). 512 threads, 8 waves. ----------
// stage1: j1 = tid>>1 (rz output 0..255), h1 = tid&1 owns 64 of 128 k's (32 f16-pair dots).
// stage2: j2 = tid>>2 (n output 0..127),  q2 = tid&3 owns 32 of 128 k's (16 f16-pair dots).
// Weights as 48 pinned u32 (packed f16 pairs); matvec via v_dot2_f32_f16.
// LDS operands packed f16, bases chosen so every wave read is a disjoint-bank broadcast.
__global__ __launch_bounds__(512, 2) void scan_kernel(
    const float* __restrict__ gi,      // [16384][768]
    const float* __restrict__ WhF, const float* __restrict__ bhF,
    const float* __restrict__ WhB, const float* __restrict__ bhB,
    float* __restrict__ hc)
{
  int dir = blockIdx.x >> 5;
  int b = blockIdx.x & 31;
  const float* Wh = dir ? WhB : WhF;
  const float* bh = dir ? bhB : bhF;
  int tid = threadIdx.x;
  int j1 = tid >> 1, h1 = tid & 1;
  int j2 = tid >> 2, q2 = tid & 3;

  __shared__ float h_s[128];                        // f32 state
  __shared__ __align__(16) unsigned hs16[68];       // f16-packed h: halves at u32 0 / 36
  __shared__ __align__(16) unsigned rh16[76];       // f16-packed rh: quarters at u32 0/20/40/60
  __shared__ float z_s[128];

  // ---- load + convert recurrent weights into 48 packed-u32 registers ----
  const float* wp1 = Wh + (size_t)j1 * 128 + h1 * 64;
#define LDA(n) unsigned A##n; { float2 t_ = *(const float2*)(wp1 + 2*(n)); A##n = packh2(t_.x, t_.y); }
  LDA(0) LDA(1) LDA(2) LDA(3) LDA(4) LDA(5) LDA(6) LDA(7)
  LDA(8) LDA(9) LDA(10) LDA(11) LDA(12) LDA(13) LDA(14) LDA(15)
  LDA(16) LDA(17) LDA(18) LDA(19) LDA(20) LDA(21) LDA(22) LDA(23)
  LDA(24) LDA(25) LDA(26) LDA(27) LDA(28) LDA(29) LDA(30) LDA(31)
#undef LDA
  const float* wp2 = Wh + (size_t)(256 + j2) * 128 + q2 * 32;
#define LDB(n) unsigned B##n; { float2 t_ = *(const float2*)(wp2 + 2*(n)); B##n = packh2(t_.x, t_.y); }
  LDB(0) LDB(1) LDB(2) LDB(3) LDB(4) LDB(5) LDB(6) LDB(7)
  LDB(8) LDB(9) LDB(10) LDB(11) LDB(12) LDB(13) LDB(14) LDB(15)
#undef LDB

  float bh1 = bh[j1];
  float bh2 = bh[256 + j2];

  if (tid < 128) h_s[tid] = 0.0f;
  if (tid < 68)  hs16[tid] = 0u;
  __syncthreads();

  size_t row0 = dir ? ((size_t)(TT-1)*BB + b) : (size_t)b;
  const float* grow = gi + row0 * 768 + dir * 384;
  long dstep = (dir ? -(long)BB : (long)BB) * 768;
  float gi1v = grow[j1];
  float gi2v = grow[256 + j2];

  for (int s = 0; s < TT; s++) {
    // pin all 48 packed-weight u32s: tied 32-bit operands force residency across the loop
#define PIN8(a,b_,c,d,e,f,g,hh) asm volatile("" : "+v"(a), "+v"(b_), "+v"(c), "+v"(d), "+v"(e), "+v"(f), "+v"(g), "+v"(hh));
    PIN8(A0,A1,A2,A3,A4,A5,A6,A7)
    PIN8(A8,A9,A10,A11,A12,A13,A14,A15)
    PIN8(A16,A17,A18,A19,A20,A21,A22,A23)
    PIN8(A24,A25,A26,A27,A28,A29,A30,A31)
    PIN8(B0,B1,B2,B3,B4,B5,B6,B7)
    PIN8(B8,B9,B10,B11,B12,B13,B14,B15)
#undef PIN8

    // prefetch next step's gi (coalesced; hidden under compute)
    const float* gnext = grow + dstep;
    float gi1n = 0.f, gi2n = 0.f;
    if (s + 1 < TT) { gi1n = gnext[j1]; gi2n = gnext[256 + j2]; }

    float hold = h_s[j1 & 127];   // old h (for r*h); conflict-free scalar reads

    // stage 1: y(j1) = sum over this lane's 64 h-elements (32 packed dot2)
    const unsigned* hp = hs16 + h1 * 36;
    float ya = 0.f, yb = 0.f, yc = 0.f, yd = 0.f;
#define S1(n, w0, w1, w2, w3) { uint4 hv = *(const uint4*)(hp + 4*(n)); \
    ya = DOT2(BCH(w0), BCH(hv.x), ya); yb = DOT2(BCH(w1), BCH(hv.y), yb); \
    yc = DOT2(BCH(w2), BCH(hv.z), yc); yd = DOT2(BCH(w3), BCH(hv.w), yd); }
    S1(0, A0,A1,A2,A3)     S1(1, A4,A5,A6,A7)
    S1(2, A8,A9,A10,A11)   S1(3, A12,A13,A14,A15)
    S1(4, A16,A17,A18,A19) S1(5, A20,A21,A22,A23)
    S1(6, A24,A25,A26,A27) S1(7, A28,A29,A30,A31)
#undef S1
    float y = (ya + yb) + (yc + yd);
    y += __shfl_xor(y, 1);
    float sg = sigmoidf_(gi1v + y + bh1);
    float rhv = sg * hold;
    float rhp = __shfl_xor(rhv, 2);     // partner's r*h (j1+1) for f16 packing
    if ((tid & 3) == 0 && j1 < 128) {
      int pi = j1 >> 1;                 // pair index 0..63
      rh16[(pi & 15) + 20 * (pi >> 4)] = packh2(rhv, rhp);
    }
    if (h1 == 0 && j1 >= 128) z_s[j1 - 128] = sg;
    __syncthreads();   // barrier A: rh/z ready

    // stage 2: y2(j2) = sum over this lane's 32 rh-elements (16 packed dot2)
    const unsigned* rp = rh16 + q2 * 20;
    float ca = 0.f, cb = 0.f, cc = 0.f, cd = 0.f;
#define S2(n, w0, w1, w2, w3) { uint4 rv = *(const uint4*)(rp + 4*(n)); \
    ca = DOT2(BCH(w0), BCH(rv.x), ca); cb = DOT2(BCH(w1), BCH(rv.y), cb); \
    cc = DOT2(BCH(w2), BCH(rv.z), cc); cd = DOT2(BCH(w3), BCH(rv.w), cd); }
    S2(0, B0,B1,B2,B3)   S2(1, B4,B5,B6,B7)
    S2(2, B8,B9,B10,B11) S2(3, B12,B13,B14,B15)
#undef S2
    float y2 = (ca + cb) + (cc + cd);
    y2 += __shfl_xor(y2, 1);
    y2 += __shfl_xor(y2, 2);
    float nn = tanhf_(gi2v + y2 + bh2);
    float zv = z_s[j2];
    float hv_ = h_s[j2];                // old h (read before in-wave write below)
    float hn = nn + zv * (hv_ - nn);    // (1-z)*n + z*h
    float hnp = __shfl_xor(hn, 4);      // partner's h_new (j2+1) for f16 packing
    if ((tid & 3) == 0) {
      h_s[j2] = hn;
      int t = dir ? (TT - 1 - s) : s;
      hc[((size_t)t * BB + b) * EE + dir * HH + j2] = hn;
    }
    if ((tid & 7) == 0) {
      int pi = j2 >> 1;                 // pair index 0..63
      hs16[(pi & 31) + 36 * (j2 >> 6)] = packh2(hn, hnp);
    }
    __syncthreads();   // barrier B: h updated for next step
    gi1v = gi1n; gi2v = gi2n;
    grow = gnext;
  }
}

// ---------- K3/K5: C[r][c] = bias[c] + sum_k A[r][k]*W[c][k]  (K=256) ----------
__global__ __launch_bounds__(256) void gemm_kernel(
    const float* __restrict__ A, const float* __restrict__ W,
    const float* __restrict__ bias, float* __restrict__ C,
    int N, int nChunks)
{
  __shared__ float As[64*258];       // padded stride 258
  __shared__ unsigned Ws[128*129];   // bf16 pairs, padded stride 129 u32
  int tid = threadIdx.x;
  int ty = tid >> 4, tx = tid & 15;
  int r0 = blockIdx.x * 64;

  for (int l = tid; l < 4096; l += 256) {        // 64 rows x 64 float4
    int row = l >> 6, kq = l & 63;
    float4 v = *(const float4*)(A + (size_t)(r0 + row)*256 + kq*4);
    float2* dst = (float2*)&As[row*258 + kq*4];
    dst[0] = make_float2(v.x, v.y);
    dst[1] = make_float2(v.z, v.w);
  }

  for (int ch = 0; ch < nChunks; ch++) {
    int c0 = ch * 128;
    __syncthreads();                               // prior reads of Ws done / As staged
    for (int l = tid; l < 8192; l += 256) {        // 128 cols x 64 float4
      int c = l >> 6, kq = l & 63;
      float4 v = *(const float4*)(W + (size_t)(c0 + c)*256 + kq*4);
      Ws[c*129 + kq*2]     = packbf(v.x, v.y);
      Ws[c*129 + kq*2 + 1] = packbf(v.z, v.w);
    }
    __syncthreads();

    float acc[4][8];
#pragma unroll
    for (int rj = 0; rj < 4; rj++)
#pragma unroll
      for (int cj = 0; cj < 8; cj++)
        acc[rj][cj] = bias[c0 + tx + 16*cj];

#pragma unroll 2
    for (int kp = 0; kp < 128; kp++) {
      float2 av[4];
#pragma unroll
      for (int rj = 0; rj < 4; rj++)
        av[rj] = *(const float2*)&As[(ty*4+rj)*258 + 2*kp];
#pragma unroll
      for (int cj = 0; cj < 8; cj++) {
        unsigned w = Ws[(tx + 16*cj)*129 + kp];
        float w0 = bflo(w), w1 = bfhi(w);
#pragma unroll
        for (int rj = 0; rj < 4; rj++)
          acc[rj][cj] += av[rj].x*w0 + av[rj].y*w1;
      }
    }
#pragma unroll
    for (int rj = 0; rj < 4; rj++)
#pragma unroll
      for (int cj = 0; cj < 8; cj++)
        C[(size_t)(r0 + ty*4 + rj)*N + c0 + tx + 16*cj] = acc[rj][cj];
  }
}

// ---------- K4: attention, one WG per (b, head) ----------
__global__ __launch_bounds__(256) void attn_kernel(
    const float* __restrict__ qkv, float* __restrict__ obuf)
{
  int b = blockIdx.x >> 3, h = blockIdx.x & 7;
  int tid = threadIdx.x;
  __shared__ unsigned short Kt[32][512];        // bf16 K^T [d][s]
  __shared__ __align__(16) float Vs[512][32];   // f32 V
  __shared__ unsigned short Sb[32][520];        // bf16 scores/probs, padded
  __shared__ float Qb[32][33];                  // f32 Q tile, padded

  for (int s = tid; s < 512; s += 256) {
    const float* kr = qkv + ((size_t)s * BB + b) * 768 + 256 + h * 32;
    const float* vr = kr + 256;
#pragma unroll
    for (int dq = 0; dq < 8; dq++) {
      float4 kv = *(const float4*)(kr + dq*4);
      float4 vv = *(const float4*)(vr + dq*4);
      Kt[dq*4+0][s] = f2bf(kv.x);
      Kt[dq*4+1][s] = f2bf(kv.y);
      Kt[dq*4+2][s] = f2bf(kv.z);
      Kt[dq*4+3][s] = f2bf(kv.w);
      *(float4*)&Vs[s][dq*4] = vv;
    }
  }

  int ty = tid >> 4, tx = tid & 15;   // scores roles: 2 rows x 8 cols
  int rr = tid >> 3, lg = tid & 7;    // softmax/PV roles
  int d0 = (tid & 7) * 4;

  for (int rb = 0; rb < 16; rb++) {
    int t0 = rb * 32;
    __syncthreads();   // K/V staged (rb=0) ; Qb/Sb free for rewrite
    for (int l = tid; l < 1024; l += 256) {
      int tr = l >> 5, d = l & 31;
      Qb[tr][d] = qkv[((size_t)(t0 + tr) * BB + b) * 768 + h * 32 + d] * 0.17677669529663687f;
    }
    __syncthreads();

    // scores
    for (int c4 = 0; c4 < 4; c4++) {
      int s0 = c4 * 128 + tx * 8;
      float acc0[8] = {0,0,0,0,0,0,0,0};
      float acc1[8] = {0,0,0,0,0,0,0,0};
#pragma unroll 8
      for (int d = 0; d < 32; d++) {
        float q0 = Qb[ty*2+0][d];
        float q1 = Qb[ty*2+1][d];
        uint4 kw = *(const uint4*)&Kt[d][s0];
        float k0 = bflo(kw.x), k1 = bfhi(kw.x);
        float k2 = bflo(kw.y), k3 = bfhi(kw.y);
        float k4 = bflo(kw.z), k5 = bfhi(kw.z);
        float k6 = bflo(kw.w), k7 = bfhi(kw.w);
        acc0[0]+=q0*k0; acc0[1]+=q0*k1; acc0[2]+=q0*k2; acc0[3]+=q0*k3;
        acc0[4]+=q0*k4; acc0[5]+=q0*k5; acc0[6]+=q0*k6; acc0[7]+=q0*k7;
        acc1[0]+=q1*k0; acc1[1]+=q1*k1; acc1[2]+=q1*k2; acc1[3]+=q1*k3;
        acc1[4]+=q1*k4; acc1[5]+=q1*k5; acc1[6]+=q1*k6; acc1[7]+=q1*k7;
      }
      unsigned* s0p = (unsigned*)&Sb[ty*2+0][s0];
      unsigned* s1p = (unsigned*)&Sb[ty*2+1][s0];
      s0p[0]=packbf(acc0[0],acc0[1]); s0p[1]=packbf(acc0[2],acc0[3]);
      s0p[2]=packbf(acc0[4],acc0[5]); s0p[3]=packbf(acc0[6],acc0[7]);
      s1p[0]=packbf(acc1[0],acc1[1]); s1p[1]=packbf(acc1[2],acc1[3]);
      s1p[2]=packbf(acc1[4],acc1[5]); s1p[3]=packbf(acc1[6],acc1[7]);
    }
    __syncthreads();

    // softmax over s (row rr, 8 lanes per row, strided columns)
    {
      unsigned* srow = (unsigned*)&Sb[rr][0];
      float vals[64];
      float m = -1e30f;
#pragma unroll
      for (int i = 0; i < 32; i++) {
        unsigned u = srow[lg + i*8];
        float va = bflo(u), vb = bfhi(u);
        vals[i*2] = va; vals[i*2+1] = vb;
        m = fmaxf(m, fmaxf(va, vb));
      }
      m = fmaxf(m, __shfl_xor(m, 1));
      m = fmaxf(m, __shfl_xor(m, 2));
      m = fmaxf(m, __shfl_xor(m, 4));
      float sum = 0.f;
#pragma unroll
      for (int i = 0; i < 64; i++) { float e = __expf(vals[i] - m); vals[i] = e; sum += e; }
      sum += __shfl_xor(sum, 1);
      sum += __shfl_xor(sum, 2);
      sum += __shfl_xor(sum, 4);
      float inv = 1.0f / sum;
#pragma unroll
      for (int i = 0; i < 32; i++)
        srow[lg + i*8] = packbf(vals[i*2]*inv, vals[i*2+1]*inv);
    }
    __syncthreads();

    // PV: o[rr][d0..d0+3]
    {
      float4 acc = make_float4(0,0,0,0);
#pragma unroll 4
      for (int s = 0; s < 512; s += 4) {
        uint2 pw = *(const uint2*)&Sb[rr][s];
        float p0 = bflo(pw.x), p1 = bfhi(pw.x), p2 = bflo(pw.y), p3 = bfhi(pw.y);
        float4 v0 = *(const float4*)&Vs[s+0][d0];
        float4 v1 = *(const float4*)&Vs[s+1][d0];
        float4 v2 = *(const float4*)&Vs[s+2][d0];
        float4 v3 = *(const float4*)&Vs[s+3][d0];
        acc.x += p0*v0.x + p1*v1.x + p2*v2.x + p3*v3.x;
        acc.y += p0*v0.y + p1*v1.y + p2*v2.y + p3*v3.y;
        acc.z += p0*v0.z + p1*v1.z + p2*v2.z + p3*v3.z;
        acc.w += p0*v0.w + p1*v1.w + p2*v2.w + p3*v3.w;
      }
      *(float4*)(obuf + ((size_t)(t0 + rr) * BB + b) * EE + h*32 + d0) = acc;
    }
  }
}

// ---------- K6: imputed = hc2 @ out_w.T + out_b ; blend ; write both outputs ----------
__global__ __launch_bounds__(256) void final_kernel(
    const float* __restrict__ A,      // hc2 [16384][256]
    const float* __restrict__ W,      // out_w [64][256]
    const float* __restrict__ bias,   // out_b [64]
    const float* __restrict__ x, const float* __restrict__ mask,
    float* __restrict__ out)          // [output | imputed], each [B][T][D]
{
  __shared__ float As[64*258];
  __shared__ unsigned Ws[64*129];
  int tid = threadIdx.x;
  int ty = tid >> 4, tx = tid & 15;
  int r0 = blockIdx.x * 64;

  for (int l = tid; l < 4096; l += 256) {
    int row = l >> 6, kq = l & 63;
    float4 v = *(const float4*)(A + (size_t)(r0 + row)*256 + kq*4);
    float2* dst = (float2*)&As[row*258 + kq*4];
    dst[0] = make_float2(v.x, v.y);
    dst[1] = make_float2(v.z, v.w);
  }
  for (int l = tid; l < 4096; l += 256) {
    int c = l >> 6, kq = l & 63;
    float4 v = *(const float4*)(W + (size_t)c*256 + kq*4);
    Ws[c*129 + kq*2]     = packbf(v.x, v.y);
    Ws[c*129 + kq*2 + 1] = packbf(v.z, v.w);
  }
  __syncthreads();

  float acc[4][4];
#pragma unroll
  for (int rj = 0; rj < 4; rj++)
#pragma unroll
    for (int cj = 0; cj < 4; cj++)
      acc[rj][cj] = bias[tx + 16*cj];

#pragma unroll 2
  for (int kp = 0; kp < 128; kp++) {
    float2 av[4];
#pragma unroll
    for (int rj = 0; rj < 4; rj++)
      av[rj] = *(const float2*)&As[(ty*4+rj)*258 + 2*kp];
#pragma unroll
    for (int cj = 0; cj < 4; cj++) {
      unsigned w = Ws[(tx + 16*cj)*129 + kp];
      float w0 = bflo(w), w1 = bfhi(w);
#pragma unroll
      for (int rj = 0; rj < 4; rj++)
        acc[rj][cj] += av[rj].x*w0 + av[rj].y*w1;
    }
  }

#pragma unroll
  for (int rj = 0; rj < 4; rj++) {
    int r = r0 + ty*4 + rj;
    int t = r >> 5, b = r & 31;
    size_t base = ((size_t)b * TT + t) * DD;
#pragma unroll
    for (int cj = 0; cj < 4; cj++) {
      int c = tx + 16*cj;
      float imp = acc[rj][cj];
      float xv = x[base + c], mv = mask[base + c];
      out[base + c] = xv*mv + imp*(1.0f - mv);
      out[(size_t)1048576 + base + c] = imp;
    }
  }
}

// ---------- launcher ----------
extern "C" void kernel_launch(void* const* d_in, const int* in_sizes, int n_in,
                              void* d_out, int out_size, void* d_ws, size_t ws_size,
                              hipStream_t stream) {
  const float* x     = (const float*)d_in[0];
  const float* mask  = (const float*)d_in[1];
  const float* fWi   = (const float*)d_in[2];
  const float* fbi   = (const float*)d_in[3];
  const float* fWh   = (const float*)d_in[4];
  const float* fbh   = (const float*)d_in[5];
  const float* bWi   = (const float*)d_in[6];
  const float* bbi   = (const float*)d_in[7];
  const float* bWh   = (const float*)d_in[8];
  const float* bbh   = (const float*)d_in[9];
  const float* aWin  = (const float*)d_in[10];
  const float* abin  = (const float*)d_in[11];
  const float* aWout = (const float*)d_in[12];
  const float* about = (const float*)d_in[13];
  const float* oW    = (const float*)d_in[14];
  const float* ob    = (const float*)d_in[15];
  float* out = (float*)d_out;
  float* ws  = (float*)d_ws;

  // workspace layout (f32 elems), with aliasing across pipeline phases:
  // [0, 12582912)        gi [16384][768]  -> later qkv [16384][768] -> later hc2 [16384][256]
  // [12582912, 16777216) hc  [16384][256] -> later obuf [16384][256]
  float* gi   = ws;
  float* hc   = ws + 12582912;
  float* qkv  = ws;
  float* obuf = ws + 12582912;
  float* hc2  = ws;

  gi_kernel<<<dim3(64, 2), 256, 0, stream>>>(x, mask, fWi, fbi, bWi, bbi, gi);
  scan_kernel<<<64, 512, 0, stream>>>(gi, fWh, fbh, bWh, bbh, hc);
  gemm_kernel<<<256, 256, 0, stream>>>(hc, aWin, abin, qkv, 768, 6);
  attn_kernel<<<256, 256, 0, stream>>>(qkv, obuf);
  gemm_kernel<<<256, 256, 0, stream>>>(obuf, aWout, about, hc2, 256, 2);
  final_kernel<<<256, 256, 0, stream>>>(hc2, oW, ob, x, mask, out);
}

// Round 5
// 1152.107 us; speedup vs baseline: 1.0967x; 1.0182x over previous
//
#include <hip/hip_runtime.h>

#define TT 512
#define BB 32
#define DD 64
#define HH 128
#define EE 256
#define NR 16384   // T*B rows

typedef _Float16 h2v __attribute__((ext_vector_type(2)));

// ---------- helpers ----------
static __device__ __forceinline__ float bflo(unsigned u){ return __uint_as_float(u << 16); }
static __device__ __forceinline__ float bfhi(unsigned u){ return __uint_as_float(u & 0xFFFF0000u); }
static __device__ __forceinline__ unsigned short f2bf(float x){
  unsigned u = __float_as_uint(x);
  return (unsigned short)((u + 0x7FFFu + ((u >> 16) & 1u)) >> 16);  // RNE
}
static __device__ __forceinline__ unsigned packbf(float a, float b){
  return (unsigned)f2bf(a) | ((unsigned)f2bf(b) << 16);
}
static __device__ __forceinline__ float sigmoidf_(float x){
  return 1.0f / (1.0f + __expf(-x));
}
static __device__ __forceinline__ float tanhf_(float x){
  float e = __expf(2.0f * x);
  return 1.0f - 2.0f / (e + 1.0f);
}
static __device__ __forceinline__ unsigned packh2(float a, float b){
  h2v v; v.x = (_Float16)a; v.y = (_Float16)b;
  return __builtin_bit_cast(unsigned, v);
}
#define BCH(u) __builtin_bit_cast(h2v, (u))
#define DOT2(a, b, c) __builtin_amdgcn_fdot2((a), (b), (c), false)

// ---------- K1: gi[r][dir*384+j] = bi[j] + sum_d (x*mask)[r][d] * Wi[j][d] ----------
__global__ __launch_bounds__(256, 2) void gi_kernel(
    const float* __restrict__ x, const float* __restrict__ mask,
    const float* __restrict__ WiF, const float* __restrict__ biF,
    const float* __restrict__ WiB, const float* __restrict__ biB,
    float* __restrict__ gi)
{
  int r = blockIdx.x * 256 + threadIdx.x;
  int dir = blockIdx.y;
  const float* Wi = dir ? WiB : WiF;
  const float* bi = dir ? biB : biF;
  int t = r >> 5, b = r & 31;
  const float* xr = x + ((size_t)b * TT + t) * DD;
  const float* mr = mask + ((size_t)b * TT + t) * DD;
  float a[64];
#pragma unroll
  for (int i = 0; i < 16; i++) {
    float4 xv = *(const float4*)(xr + i*4);
    float4 mv = *(const float4*)(mr + i*4);
    a[i*4+0] = xv.x*mv.x; a[i*4+1] = xv.y*mv.y; a[i*4+2] = xv.z*mv.z; a[i*4+3] = xv.w*mv.w;
  }
  float* g = gi + (size_t)r * 768 + dir * 384;
  for (int j = 0; j < 384; j += 4) {
    float acc0 = bi[j+0], acc1 = bi[j+1], acc2 = bi[j+2], acc3 = bi[j+3];
    const float* w = Wi + (size_t)j * 64;
#pragma unroll
    for (int k = 0; k < 64; k++) {
      float av = a[k];
      acc0 += av * w[k];
      acc1 += av * w[64 + k];
      acc2 += av * w[128 + k];
      acc3 += av * w[192 + k];
    }
    *(float4*)(g + j) = make_float4(acc0, acc1, acc2, acc3);
  }
}

// ---------- K2: GRU scan. One WG per (dir, b). 512 threads, 8 waves. ----------
// stage1: j1 = tid>>1 (rz output 0..255), h1 = tid&1 owns 64 of 128 k's (32 f16-pair dots).
// stage2: j2 = tid>>2 (n output 0..127),  q2 = tid&3 owns 32 of 128 k's (16 f16-pair dots).
// Weights as 48 pinned u32 (packed f16 pairs); matvec via v_dot2_f32_f16.
// amdgpu_waves_per_eu(2,2): caps occupancy target -> RA gets a 256-VGPR budget
// and actually KEEPS the 48 weight u32s resident (R4's VGPR=56 showed the
// default occupancy heuristic rematerializes them from L2 every step).
__global__ __launch_bounds__(512)
__attribute__((amdgpu_waves_per_eu(2, 2)))
void scan_kernel(
    const float* __restrict__ gi,      // [16384][768]
    const float* __restrict__ WhF, const float* __restrict__ bhF,
    const float* __restrict__ WhB, const float* __restrict__ bhB,
    float* __restrict__ hc)
{
  int dir = blockIdx.x >> 5;
  int b = blockIdx.x & 31;
  const float* Wh = dir ? WhB : WhF;
  const float* bh = dir ? bhB : bhF;
  int tid = threadIdx.x;
  int j1 = tid >> 1, h1 = tid & 1;
  int j2 = tid >> 2, q2 = tid & 3;

  __shared__ float h_s[128];                        // f32 state
  __shared__ __align__(16) unsigned hs16[68];       // f16-packed h: halves at u32 0 / 36
  __shared__ __align__(16) unsigned rh16[76];       // f16-packed rh: quarters at u32 0/20/40/60
  __shared__ float z_s[128];

  // ---- load + convert recurrent weights into 48 packed-u32 registers ----
  const float* wp1 = Wh + (size_t)j1 * 128 + h1 * 64;
#define LDA(n) unsigned A##n; { float2 t_ = *(const float2*)(wp1 + 2*(n)); A##n = packh2(t_.x, t_.y); }
  LDA(0) LDA(1) LDA(2) LDA(3) LDA(4) LDA(5) LDA(6) LDA(7)
  LDA(8) LDA(9) LDA(10) LDA(11) LDA(12) LDA(13) LDA(14) LDA(15)
  LDA(16) LDA(17) LDA(18) LDA(19) LDA(20) LDA(21) LDA(22) LDA(23)
  LDA(24) LDA(25) LDA(26) LDA(27) LDA(28) LDA(29) LDA(30) LDA(31)
#undef LDA
  const float* wp2 = Wh + (size_t)(256 + j2) * 128 + q2 * 32;
#define LDB(n) unsigned B##n; { float2 t_ = *(const float2*)(wp2 + 2*(n)); B##n = packh2(t_.x, t_.y); }
  LDB(0) LDB(1) LDB(2) LDB(3) LDB(4) LDB(5) LDB(6) LDB(7)
  LDB(8) LDB(9) LDB(10) LDB(11) LDB(12) LDB(13) LDB(14) LDB(15)
#undef LDB

  float bh1 = bh[j1];
  float bh2 = bh[256 + j2];

  if (tid < 128) h_s[tid] = 0.0f;
  if (tid < 68)  hs16[tid] = 0u;
  __syncthreads();

  size_t row0 = dir ? ((size_t)(TT-1)*BB + b) : (size_t)b;
  const float* grow = gi + row0 * 768 + dir * 384;
  long dstep = (dir ? -(long)BB : (long)BB) * 768;
  float gi1v = grow[j1];
  float gi2v = grow[256 + j2];

  for (int s = 0; s < TT; s++) {
    // pin all 48 packed-weight u32s: tied 32-bit operands, loop-carried
#define PIN8(a,b_,c,d,e,f,g,hh) asm volatile("" : "+v"(a), "+v"(b_), "+v"(c), "+v"(d), "+v"(e), "+v"(f), "+v"(g), "+v"(hh));
    PIN8(A0,A1,A2,A3,A4,A5,A6,A7)
    PIN8(A8,A9,A10,A11,A12,A13,A14,A15)
    PIN8(A16,A17,A18,A19,A20,A21,A22,A23)
    PIN8(A24,A25,A26,A27,A28,A29,A30,A31)
    PIN8(B0,B1,B2,B3,B4,B5,B6,B7)
    PIN8(B8,B9,B10,B11,B12,B13,B14,B15)
#undef PIN8

    // prefetch next step's gi (coalesced; hidden under compute)
    const float* gnext = grow + dstep;
    float gi1n = 0.f, gi2n = 0.f;
    if (s + 1 < TT) { gi1n = gnext[j1]; gi2n = gnext[256 + j2]; }

    float hold = h_s[j1 & 127];   // old h (for r*h); conflict-free scalar reads

    // stage 1: y(j1) = sum over this lane's 64 h-elements (32 packed dot2)
    const unsigned* hp = hs16 + h1 * 36;
    float ya = 0.f, yb = 0.f, yc = 0.f, yd = 0.f;
#define S1(n, w0, w1, w2, w3) { uint4 hv = *(const uint4*)(hp + 4*(n)); \
    ya = DOT2(BCH(w0), BCH(hv.x), ya); yb = DOT2(BCH(w1), BCH(hv.y), yb); \
    yc = DOT2(BCH(w2), BCH(hv.z), yc); yd = DOT2(BCH(w3), BCH(hv.w), yd); }
    S1(0, A0,A1,A2,A3)     S1(1, A4,A5,A6,A7)
    S1(2, A8,A9,A10,A11)   S1(3, A12,A13,A14,A15)
    S1(4, A16,A17,A18,A19) S1(5, A20,A21,A22,A23)
    S1(6, A24,A25,A26,A27) S1(7, A28,A29,A30,A31)
#undef S1
    float y = (ya + yb) + (yc + yd);
    y += __shfl_xor(y, 1);
    float sg = sigmoidf_(gi1v + y + bh1);
    float rhv = sg * hold;
    float rhp = __shfl_xor(rhv, 2);     // partner's r*h (j1+1) for f16 packing
    if ((tid & 3) == 0 && j1 < 128) {
      int pi = j1 >> 1;                 // pair index 0..63
      rh16[(pi & 15) + 20 * (pi >> 4)] = packh2(rhv, rhp);
    }
    if (h1 == 0 && j1 >= 128) z_s[j1 - 128] = sg;
    __syncthreads();   // barrier A: rh/z ready

    // stage 2: y2(j2) = sum over this lane's 32 rh-elements (16 packed dot2)
    const unsigned* rp = rh16 + q2 * 20;
    float ca = 0.f, cb = 0.f, cc = 0.f, cd = 0.f;
#define S2(n, w0, w1, w2, w3) { uint4 rv = *(const uint4*)(rp + 4*(n)); \
    ca = DOT2(BCH(w0), BCH(rv.x), ca); cb = DOT2(BCH(w1), BCH(rv.y), cb); \
    cc = DOT2(BCH(w2), BCH(rv.z), cc); cd = DOT2(BCH(w3), BCH(rv.w), cd); }
    S2(0, B0,B1,B2,B3)   S2(1, B4,B5,B6,B7)
    S2(2, B8,B9,B10,B11) S2(3, B12,B13,B14,B15)
#undef S2
    float y2 = (ca + cb) + (cc + cd);
    y2 += __shfl_xor(y2, 1);
    y2 += __shfl_xor(y2, 2);
    float nn = tanhf_(gi2v + y2 + bh2);
    float zv = z_s[j2];
    float hv_ = h_s[j2];                // old h (read before in-wave write below)
    float hn = nn + zv * (hv_ - nn);    // (1-z)*n + z*h
    float hnp = __shfl_xor(hn, 4);      // partner's h_new (j2+1) for f16 packing
    if ((tid & 3) == 0) {
      h_s[j2] = hn;
      int t = dir ? (TT - 1 - s) : s;
      hc[((size_t)t * BB + b) * EE + dir * HH + j2] = hn;
    }
    if ((tid & 7) == 0) {
      int pi = j2 >> 1;                 // pair index 0..63
      hs16[(pi & 31) + 36 * (j2 >> 6)] = packh2(hn, hnp);
    }
    __syncthreads();   // barrier B: h updated for next step
    gi1v = gi1n; gi2v = gi2n;
    grow = gnext;
  }
}

// ---------- K3/K5: C[r][c] = bias[c] + sum_k A[r][k]*W[c][k]  (K=256) ----------
// As stride 260 (16B-aligned float4 reads), Ws stride 130 (8B-aligned uint2 reads);
// inner loop processes 4 k's per iteration -> half the LDS instruction count.
__global__ __launch_bounds__(256) void gemm_kernel(
    const float* __restrict__ A, const float* __restrict__ W,
    const float* __restrict__ bias, float* __restrict__ C,
    int N, int nChunks)
{
  __shared__ float As[64*260];       // padded stride 260
  __shared__ unsigned Ws[128*130];   // bf16 pairs, padded stride 130 u32
  int tid = threadIdx.x;
  int ty = tid >> 4, tx = tid & 15;
  int r0 = blockIdx.x * 64;

  for (int l = tid; l < 4096; l += 256) {        // 64 rows x 64 float4
    int row = l >> 6, kq = l & 63;
    float4 v = *(const float4*)(A + (size_t)(r0 + row)*256 + kq*4);
    *(float4*)&As[row*260 + kq*4] = v;
  }

  for (int ch = 0; ch < nChunks; ch++) {
    int c0 = ch * 128;
    __syncthreads();                               // prior reads of Ws done / As staged
    for (int l = tid; l < 8192; l += 256) {        // 128 cols x 64 float4
      int c = l >> 6, kq = l & 63;
      float4 v = *(const float4*)(W + (size_t)(c0 + c)*256 + kq*4);
      uint2 p; p.x = packbf(v.x, v.y); p.y = packbf(v.z, v.w);
      *(uint2*)&Ws[c*130 + kq*2] = p;
    }
    __syncthreads();

    float acc[4][8];
#pragma unroll
    for (int rj = 0; rj < 4; rj++)
#pragma unroll
      for (int cj = 0; cj < 8; cj++)
        acc[rj][cj] = bias[c0 + tx + 16*cj];

#pragma unroll 2
    for (int kq = 0; kq < 64; kq++) {   // 4 k's per iteration
      float4 av[4];
#pragma unroll
      for (int rj = 0; rj < 4; rj++)
        av[rj] = *(const float4*)&As[(ty*4+rj)*260 + 4*kq];
#pragma unroll
      for (int cj = 0; cj < 8; cj++) {
        uint2 w2 = *(const uint2*)&Ws[(tx + 16*cj)*130 + 2*kq];
        float w0 = bflo(w2.x), w1 = bfhi(w2.x);
        float w2f = bflo(w2.y), w3 = bfhi(w2.y);
#pragma unroll
        for (int rj = 0; rj < 4; rj++)
          acc[rj][cj] += av[rj].x*w0 + av[rj].y*w1 + av[rj].z*w2f + av[rj].w*w3;
      }
    }
#pragma unroll
    for (int rj = 0; rj < 4; rj++)
#pragma unroll
      for (int cj = 0; cj < 8; cj++)
        C[(size_t)(r0 + ty*4 + rj)*N + c0 + tx + 16*cj] = acc[rj][cj];
  }
}

// ---------- K4: attention, one WG per (b, head) ----------
__global__ __launch_bounds__(256) void attn_kernel(
    const float* __restrict__ qkv, float* __restrict__ obuf)
{
  int b = blockIdx.x >> 3, h = blockIdx.x & 7;
  int tid = threadIdx.x;
  __shared__ unsigned short Kt[32][512];        // bf16 K^T [d][s]
  __shared__ __align__(16) float Vs[512][32];   // f32 V
  __shared__ unsigned short Sb[32][520];        // bf16 scores/probs, padded
  __shared__ float Qb[32][33];                  // f32 Q tile, padded

  for (int s = tid; s < 512; s += 256) {
    const float* kr = qkv + ((size_t)s * BB + b) * 768 + 256 + h * 32;
    const float* vr = kr + 256;
#pragma unroll
    for (int dq = 0; dq < 8; dq++) {
      float4 kv = *(const float4*)(kr + dq*4);
      float4 vv = *(const float4*)(vr + dq*4);
      Kt[dq*4+0][s] = f2bf(kv.x);
      Kt[dq*4+1][s] = f2bf(kv.y);
      Kt[dq*4+2][s] = f2bf(kv.z);
      Kt[dq*4+3][s] = f2bf(kv.w);
      *(float4*)&Vs[s][dq*4] = vv;
    }
  }

  int ty = tid >> 4, tx = tid & 15;   // scores roles: 2 rows x 8 cols
  int rr = tid >> 3, lg = tid & 7;    // softmax/PV roles
  int d0 = (tid & 7) * 4;

  for (int rb = 0; rb < 16; rb++) {
    int t0 = rb * 32;
    __syncthreads();   // K/V staged (rb=0) ; Qb/Sb free for rewrite
    for (int l = tid; l < 1024; l += 256) {
      int tr = l >> 5, d = l & 31;
      Qb[tr][d] = qkv[((size_t)(t0 + tr) * BB + b) * 768 + h * 32 + d] * 0.17677669529663687f;
    }
    __syncthreads();

    // scores
    for (int c4 = 0; c4 < 4; c4++) {
      int s0 = c4 * 128 + tx * 8;
      float acc0[8] = {0,0,0,0,0,0,0,0};
      float acc1[8] = {0,0,0,0,0,0,0,0};
#pragma unroll 8
      for (int d = 0; d < 32; d++) {
        float q0 = Qb[ty*2+0][d];
        float q1 = Qb[ty*2+1][d];
        uint4 kw = *(const uint4*)&Kt[d][s0];
        float k0 = bflo(kw.x), k1 = bfhi(kw.x);
        float k2 = bflo(kw.y), k3 = bfhi(kw.y);
        float k4 = bflo(kw.z), k5 = bfhi(kw.z);
        float k6 = bflo(kw.w), k7 = bfhi(kw.w);
        acc0[0]+=q0*k0; acc0[1]+=q0*k1; acc0[2]+=q0*k2; acc0[3]+=q0*k3;
        acc0[4]+=q0*k4; acc0[5]+=q0*k5; acc0[6]+=q0*k6; acc0[7]+=q0*k7;
        acc1[0]+=q1*k0; acc1[1]+=q1*k1; acc1[2]+=q1*k2; acc1[3]+=q1*k3;
        acc1[4]+=q1*k4; acc1[5]+=q1*k5; acc1[6]+=q1*k6; acc1[7]+=q1*k7;
      }
      unsigned* s0p = (unsigned*)&Sb[ty*2+0][s0];
      unsigned* s1p = (unsigned*)&Sb[ty*2+1][s0];
      s0p[0]=packbf(acc0[0],acc0[1]); s0p[1]=packbf(acc0[2],acc0[3]);
      s0p[2]=packbf(acc0[4],acc0[5]); s0p[3]=packbf(acc0[6],acc0[7]);
      s1p[0]=packbf(acc1[0],acc1[1]); s1p[1]=packbf(acc1[2],acc1[3]);
      s1p[2]=packbf(acc1[4],acc1[5]); s1p[3]=packbf(acc1[6],acc1[7]);
    }
    __syncthreads();

    // softmax over s (row rr, 8 lanes per row, strided columns)
    {
      unsigned* srow = (unsigned*)&Sb[rr][0];
      float vals[64];
      float m = -1e30f;
#pragma unroll
      for (int i = 0; i < 32; i++) {
        unsigned u = srow[lg + i*8];
        float va = bflo(u), vb = bfhi(u);
        vals[i*2] = va; vals[i*2+1] = vb;
        m = fmaxf(m, fmaxf(va, vb));
      }
      m = fmaxf(m, __shfl_xor(m, 1));
      m = fmaxf(m, __shfl_xor(m, 2));
      m = fmaxf(m, __shfl_xor(m, 4));
      float sum = 0.f;
#pragma unroll
      for (int i = 0; i < 64; i++) { float e = __expf(vals[i] - m); vals[i] = e; sum += e; }
      sum += __shfl_xor(sum, 1);
      sum += __shfl_xor(sum, 2);
      sum += __shfl_xor(sum, 4);
      float inv = 1.0f / sum;
#pragma unroll
      for (int i = 0; i < 32; i++)
        srow[lg + i*8] = packbf(vals[i*2]*inv, vals[i*2+1]*inv);
    }
    __syncthreads();

    // PV: o[rr][d0..d0+3]
    {
      float4 acc = make_float4(0,0,0,0);
#pragma unroll 4
      for (int s = 0; s < 512; s += 4) {
        uint2 pw = *(const uint2*)&Sb[rr][s];
        float p0 = bflo(pw.x), p1 = bfhi(pw.x), p2 = bflo(pw.y), p3 = bfhi(pw.y);
        float4 v0 = *(const float4*)&Vs[s+0][d0];
        float4 v1 = *(const float4*)&Vs[s+1][d0];
        float4 v2 = *(const float4*)&Vs[s+2][d0];
        float4 v3 = *(const float4*)&Vs[s+3][d0];
        acc.x += p0*v0.x + p1*v1.x + p2*v2.x + p3*v3.x;
        acc.y += p0*v0.y + p1*v1.y + p2*v2.y + p3*v3.y;
        acc.z += p0*v0.z + p1*v1.z + p2*v2.z + p3*v3.z;
        acc.w += p0*v0.w + p1*v1.w + p2*v2.w + p3*v3.w;
      }
      *(float4*)(obuf + ((size_t)(t0 + rr) * BB + b) * EE + h*32 + d0) = acc;
    }
  }
}

// ---------- K6: imputed = hc2 @ out_w.T + out_b ; blend ; write both outputs ----------
__global__ __launch_bounds__(256) void final_kernel(
    const float* __restrict__ A,      // hc2 [16384][256]
    const float* __restrict__ W,      // out_w [64][256]
    const float* __restrict__ bias,   // out_b [64]
    const float* __restrict__ x, const float* __restrict__ mask,
    float* __restrict__ out)          // [output | imputed], each [B][T][D]
{
  __shared__ float As[64*260];
  __shared__ unsigned Ws[64*130];
  int tid = threadIdx.x;
  int ty = tid >> 4, tx = tid & 15;
  int r0 = blockIdx.x * 64;

  for (int l = tid; l < 4096; l += 256) {
    int row = l >> 6, kq = l & 63;
    float4 v = *(const float4*)(A + (size_t)(r0 + row)*256 + kq*4);
    *(float4*)&As[row*260 + kq*4] = v;
  }
  for (int l = tid; l < 4096; l += 256) {
    int c = l >> 6, kq = l & 63;
    float4 v = *(const float4*)(W + (size_t)c*256 + kq*4);
    uint2 p; p.x = packbf(v.x, v.y); p.y = packbf(v.z, v.w);
    *(uint2*)&Ws[c*130 + kq*2] = p;
  }
  __syncthreads();

  float acc[4][4];
#pragma unroll
  for (int rj = 0; rj < 4; rj++)
#pragma unroll
    for (int cj = 0; cj < 4; cj++)
      acc[rj][cj] = bias[tx + 16*cj];

#pragma unroll 2
  for (int kq = 0; kq < 64; kq++) {
    float4 av[4];
#pragma unroll
    for (int rj = 0; rj < 4; rj++)
      av[rj] = *(const float4*)&As[(ty*4+rj)*260 + 4*kq];
#pragma unroll
    for (int cj = 0; cj < 4; cj++) {
      uint2 w2 = *(const uint2*)&Ws[(tx + 16*cj)*130 + 2*kq];
      float w0 = bflo(w2.x), w1 = bfhi(w2.x);
      float w2f = bflo(w2.y), w3 = bfhi(w2.y);
#pragma unroll
      for (int rj = 0; rj < 4; rj++)
        acc[rj][cj] += av[rj].x*w0 + av[rj].y*w1 + av[rj].z*w2f + av[rj].w*w3;
    }
  }

#pragma unroll
  for (int rj = 0; rj < 4; rj++) {
    int r = r0 + ty*4 + rj;
    int t = r >> 5, b = r & 31;
    size_t base = ((size_t)b * TT + t) * DD;
#pragma unroll
    for (int cj = 0; cj < 4; cj++) {
      int c = tx + 16*cj;
      float imp = acc[rj][cj];
      float xv = x[base + c], mv = mask[base + c];
      out[base + c] = xv*mv + imp*(1.0f - mv);
      out[(size_t)1048576 + base + c] = imp;
    }
  }
}

// ---------- launcher ----------
extern "C" void kernel_launch(void* const* d_in, const int* in_sizes, int n_in,
                              void* d_out, int out_size, void* d_ws, size_t ws_size,
                              hipStream_t stream) {
  const float* x     = (const float*)d_in[0];
  const float* mask  = (const float*)d_in[1];
  const float* fWi   = (const float*)d_in[2];
  const float* fbi   = (const float*)d_in[3];
  const float* fWh   = (const float*)d_in[4];
  const float* fbh   = (const float*)d_in[5];
  const float* bWi   = (const float*)d_in[6];
  const float* bbi   = (const float*)d_in[7];
  const float* bWh   = (const float*)d_in[8];
  const float* bbh   = (const float*)d_in[9];
  const float* aWin  = (const float*)d_in[10];
  const float* abin  = (const float*)d_in[11];
  const float* aWout = (const float*)d_in[12];
  const float* about = (const float*)d_in[13];
  const float* oW    = (const float*)d_in[14];
  const float* ob    = (const float*)d_in[15];
  float* out = (float*)d_out;
  float* ws  = (float*)d_ws;

  // workspace layout (f32 elems), with aliasing across pipeline phases:
  // [0, 12582912)        gi [16384][768]  -> later qkv [16384][768] -> later hc2 [16384][256]
  // [12582912, 16777216) hc  [16384][256] -> later obuf [16384][256]
  float* gi   = ws;
  float* hc   = ws + 12582912;
  float* qkv  = ws;
  float* obuf = ws + 12582912;
  float* hc2  = ws;

  gi_kernel<<<dim3(64, 2), 256, 0, stream>>>(x, mask, fWi, fbi, bWi, bbi, gi);
  scan_kernel<<<64, 512, 0, stream>>>(gi, fWh, fbh, bWh, bbh, hc);
  gemm_kernel<<<256, 256, 0, stream>>>(hc, aWin, abin, qkv, 768, 6);
  attn_kernel<<<256, 256, 0, stream>>>(qkv, obuf);
  gemm_kernel<<<256, 256, 0, stream>>>(obuf, aWout, about, hc2, 256, 2);
  final_kernel<<<256, 256, 0, stream>>>(hc2, oW, ob, x, mask, out);
}